// Round 7
// baseline (860.306 us; speedup 1.0000x reference)
//
#include <hip/hip_runtime.h>
#include <cmath>

#define DEV __device__ __forceinline__

typedef __bf16 bf16x8 __attribute__((ext_vector_type(8)));
typedef float f32x4v __attribute__((ext_vector_type(4)));
typedef unsigned short u16x8 __attribute__((ext_vector_type(8)));
typedef unsigned short u16x4 __attribute__((ext_vector_type(4)));

DEV float bf2f(unsigned short u){ return __uint_as_float(((unsigned)u)<<16); }
DEV unsigned short f2bf(float f){
  unsigned u = __float_as_uint(f);
  u = (u + 0x7fffu + ((u>>16)&1u)) >> 16;
  return (unsigned short)u;
}
DEV float geluf(float x){ return 0.5f*x*(1.0f + erff(x*0.7071067811865475f)); }

#define GLDS16(g,l) __builtin_amdgcn_global_load_lds(\
    (const __attribute__((address_space(1))) void*)(g), \
    (__attribute__((address_space(3))) void*)(l), 16, 0, 0)

// ---- problem constants ----
#define NB    4
#define NSEQ  2048
#define DDIM  512
#define MROWS 8192   // NB*NSEQ

// ---- workspace layout (bytes) ----
#define OFF_H     0u           // f32  8192x512   (16M)
#define OFF_HB    16777216u    // bf16 8192x512   (8M)
#define OFF_GP    25165824u    // bf16 8192x512   (8M)  (prep: A2/B2 live here first)
#define OFF_R     33554432u    // f32  8192x512   (16M) (overwrites GSC region after gemm1 consumed it)
#define OFF_GSC   41943040u    // bf16 8192x512   (8M)
#define OFF_WUV   50331648u    // bf16 1024x512 (Wuv^T: rows 0..511 = msgW1_top cols, 512..1023 = msgW1_bot cols)
#define OFF_WP    51380224u    // bf16 512x1024 (Wp^T: [updW1_top^T | (msgW2@updW1_bot)^T])
#define OFF_WR    52428800u    // bf16 512x512  (updW2^T)
#define OFF_BUV   52953088u    // f32[1024]  (mb1 | zeros)
#define OFF_BP    52957184u    // f32[512]
#define OFF_BR    52959232u    // f32[512]
#define OFF_DOT   52961280u    // f32[8192] per-row halt-dot partials (32K)
#define OFF_SCAL  52994048u    // f32: [0..3] remaining, [4..7] w_step, [8] kl
#define OFF_FLAGS 52994112u    // int: [0] active, [1] done
// prep-only (aliases GP; dead before first gemm1 writes GP):
#define OFF_A2    25165824u    // bf16 512x512: (uW1_bot)^T
#define OFF_B2    25690112u    // bf16 512x512: mW2

// ================= prep: LDS-tiled 512x512 f32->bf16 transposes =================
__global__ __launch_bounds__(256) void k_prep_tr(
    const float* __restrict__ mW1, const float* __restrict__ uW2,
    const float* __restrict__ uW1,
    unsigned short* __restrict__ Wuv, unsigned short* __restrict__ Wr,
    unsigned short* __restrict__ Wp,  unsigned short* __restrict__ A2)
{
  __shared__ float t[64][65];
  const int tid = threadIdx.x, c = tid&63, r4 = tid>>6;
  const float* src; unsigned short* dst; int dld;
  switch (blockIdx.y){
    case 0: src = mW1;          dst = Wuv;          dld = 512;  break;
    case 1: src = mW1 + 262144; dst = Wuv + 262144; dld = 512;  break;
    case 2: src = uW2;          dst = Wr;           dld = 512;  break;
    case 3: src = uW1;          dst = Wp;           dld = 1024; break;
    default:src = uW1 + 262144; dst = A2;           dld = 512;  break;
  }
  const int k0 = (blockIdx.x>>3)<<6, n0 = (blockIdx.x&7)<<6;
  #pragma unroll
  for (int i=0;i<16;++i){ int r = i*4 + r4; t[r][c] = src[(size_t)(k0+r)*512 + n0 + c]; }
  __syncthreads();
  #pragma unroll
  for (int i=0;i<16;++i){ int r = i*4 + r4; dst[(size_t)(n0+r)*dld + k0 + c] = f2bf(t[c][r]); }
}

// B2 copy + biasUV + biasR
__global__ __launch_bounds__(256) void k_prep_small(
    const float* __restrict__ mW2, const float* __restrict__ mb1,
    const float* __restrict__ ub2,
    unsigned short* __restrict__ B2, float* __restrict__ biasUV,
    float* __restrict__ biasR)
{
  int idx = blockIdx.x*256 + threadIdx.x;
  if (idx < 262144)      B2[idx] = f2bf(mW2[idx]);
  else if (idx < 263168){ int j = idx-262144; biasUV[j] = (j<512)? mb1[j] : 0.f; }
  else if (idx < 263680){ int j = idx-263168; biasR[j] = ub2[j]; }
}

// biasP[n] = upd_b1[n] + msg_b2 @ updW1_bot[:,n]
__global__ __launch_bounds__(256) void k_prep_biasP(
    const float* __restrict__ ub1, const float* __restrict__ mb2,
    const float* __restrict__ uW1, float* __restrict__ biasP)
{
  int n = blockIdx.x*256 + threadIdx.x;
  float s = ub1[n];
  for (int j=0;j<512;++j) s += mb2[j]*uW1[(512+j)*512+n];
  biasP[n] = s;
}

__global__ void k_init_state(float* scal, int* flags){
  int t = threadIdx.x;
  if (t<4) scal[t]=1.f;
  else if (t<9) scal[t]=0.f;
  if (t==9){ flags[0]=1; flags[1]=0; }
}

__global__ __launch_bounds__(256) void k_init_h(
    const float* __restrict__ S, float* __restrict__ H, u16x4* __restrict__ Hb)
{
  size_t idx = (size_t)blockIdx.x*256 + threadIdx.x;   // float4 units, < 1048576
  float4 v = ((const float4*)S)[idx];
  ((float4*)H)[idx] = v;
  u16x4 o; o[0]=f2bf(v.x); o[1]=f2bf(v.y); o[2]=f2bf(v.z); o[3]=f2bf(v.w);
  Hb[idx] = o;
}

// ================= MFMA GEMM: C = A(Mx512 bf16 [A1 for k>=ksplit*64]) @ Bt^T =================
// 128x64 tile, BK=64, 4 waves 2x2, double-buffered LDS, counted-vmcnt pipeline (R6 proven).
template<int EPI>  // 0: bias+bf16 out, 1: bias+gelu+bf16 out, 2: bias+f32 out
__global__ __launch_bounds__(256) void k_gemm(
    const unsigned short* __restrict__ A0, const unsigned short* __restrict__ A1,
    const unsigned short* __restrict__ Bt, const float* __restrict__ bias,
    void* __restrict__ Cout, int ldc, int ldb, int nK, int ksplit, int gridN,
    const int* __restrict__ flags)
{
  if (flags[0]==0) return;
  __shared__ unsigned short sm[2][12288];
  const int tid = threadIdx.x;
  const int bid = blockIdx.x;
  const int nb  = (int)gridDim.x;
  const int ppx = (nb>>3)/gridN;
  int mp, np;
  if (ppx*gridN*8 == nb){ const int xcd = bid&7, ib = bid>>3; mp = xcd*ppx + ib/gridN; np = ib%gridN; }
  else                  { mp = bid/gridN; np = bid%gridN; }
  const int m0 = mp<<7, n0 = np<<6;
  const int sr = tid>>3;
  const int scA = (((tid&7) ^ (sr&7)) << 3);
  const int lane = tid&63, wv = tid>>6, wr = wv>>1, wc = wv&1;
  const int la = lane&15, lg = lane>>4;
  const int swzr = (la&7)<<3;
  f32x4v acc[4][2] = {};

  auto stage = [&](int ks, int bufi){                  // 6 GLDS16 per thread
    const unsigned short* As = (ks<ksplit)? A0 : A1;
    const int kc = ((ks<ksplit)? ks : (ks-ksplit))<<6;
    unsigned short* s = sm[bufi];
    #pragma unroll
    for (int i=0;i<4;++i)
      GLDS16(As + (size_t)(m0 + i*32 + sr)*512 + kc + scA, s + i*2048 + tid*8);
    #pragma unroll
    for (int i=0;i<2;++i)
      GLDS16(Bt + (size_t)(n0 + i*32 + sr)*ldb + (ks<<6) + scA, s + 8192 + i*2048 + tid*8);
  };

  stage(0, 0);
  if (nK > 1) stage(1, 1);
  for (int ks=0; ks<nK; ++ks){
    const int cur = ks & 1;
    if (ks+1 < nK) asm volatile("s_waitcnt vmcnt(6)" ::: "memory");
    else           asm volatile("s_waitcnt vmcnt(0)" ::: "memory");
    __builtin_amdgcn_s_barrier();
    asm volatile("" ::: "memory");
    const unsigned short* s = sm[cur];
    #pragma unroll
    for (int kk=0;kk<2;++kk){
      bf16x8 af[4], bfr[2];
      #pragma unroll
      for (int mi=0;mi<4;++mi)
        af[mi] = *(const bf16x8*)(s + ((wr<<6) + (mi<<4) + la)*64 + (((kk<<5) + (lg<<3)) ^ swzr));
      #pragma unroll
      for (int ni=0;ni<2;++ni)
        bfr[ni] = *(const bf16x8*)(s + 8192 + ((wc<<5) + (ni<<4) + la)*64 + (((kk<<5) + (lg<<3)) ^ swzr));
      #pragma unroll
      for (int mi=0;mi<4;++mi)
        #pragma unroll
        for (int ni=0;ni<2;++ni)
          acc[mi][ni] = __builtin_amdgcn_mfma_f32_16x16x32_bf16(af[mi], bfr[ni], acc[mi][ni], 0, 0, 0);
    }
    asm volatile("" ::: "memory");
    __builtin_amdgcn_s_barrier();
    asm volatile("" ::: "memory");
    if (ks+2 < nK) stage(ks+2, cur);
  }

  const int r0 = m0 + (wr<<6) + (lg<<2);
  const int c0 = n0 + (wc<<5) + la;
  #pragma unroll
  for (int mi=0;mi<4;++mi){
    #pragma unroll
    for (int ni=0;ni<2;++ni){
      const int col = c0 + (ni<<4);
      const float bs = bias[col];
      #pragma unroll
      for (int r=0;r<4;++r){
        const int row = r0 + (mi<<4) + r;
        float v = acc[mi][ni][r] + bs;
        if constexpr (EPI==1) v = geluf(v);
        if constexpr (EPI==2) ((float*)Cout)[(size_t)row*ldc + col] = v;
        else ((unsigned short*)Cout)[(size_t)row*ldc + col] = f2bf(v);
      }
    }
  }
}

// ================= fused gemm0+geluacc: G = windowed-gelu( Hb@W1top , Hb@W1bot ) =================
// Per 128x64 tile: U acc (4x2), V acc (4x2) + 16-row extra V fragment (rows m0-16..m0-1,
// wr==0 waves only) so the causal window d=1..4 never crosses the block boundary.
// Epilogue: V -> LDS [144][65] f32 (aliases dead staging), then per-row
// G[i] = sum_{d<=min(i&2047,4)} gelu(U[i]+V[i-d]) / cnt, written bf16.
// LDS/buf: A 8192 | Aex 1024 | B(U) 4096 | B(V) 4096 = 17408 shorts; x2 dbuf = 69632 B.
__global__ __launch_bounds__(256) void k_gmsg(
    const unsigned short* __restrict__ Hb, const unsigned short* __restrict__ Wuv,
    const float* __restrict__ biasU, unsigned short* __restrict__ G,
    const int* __restrict__ flags)
{
  if (flags[0]==0) return;
  __shared__ __align__(16) unsigned short smraw[2*17408];
  const int tid = threadIdx.x;
  const int bid = blockIdx.x;                 // grid 512 = 8 xcd * 8 mp * 8 np
  const int xcd = bid & 7, ib = bid >> 3;
  const int mp = xcd*8 + (ib>>3), np = ib & 7;
  const int m0 = mp<<7, n0 = np<<6;
  const int sr = tid>>3;
  const int scA = (((tid&7) ^ (sr&7)) << 3);
  const int lane = tid&63, wv = tid>>6, wr = wv>>1, wc = wv&1;
  const int la = lane&15, lg = lane>>4;
  const int swzr = (la&7)<<3;
  f32x4v aU[4][2] = {}, aV[4][2] = {}, aX[2] = {};
  const int xbase = (m0==0) ? 0 : (m0-16);    // clamped; m0==0 extra rows never read

  auto stage = [&](int ks, int bufi){         // 9 loads (wv<2) or 8 loads per thread
    const int kc = ks<<6;
    unsigned short* s = smraw + bufi*17408;
    #pragma unroll
    for (int i=0;i<4;++i)                     // A main rows m0..m0+127
      GLDS16(Hb + (size_t)(m0 + i*32 + sr)*512 + kc + scA, s + i*2048 + tid*8);
    if (wv < 2)                               // A extra rows xbase..xbase+15 (2 waves x 1KB)
      GLDS16(Hb + (size_t)(xbase + sr)*512 + kc + scA, s + 8192 + tid*8);
    #pragma unroll
    for (int i=0;i<2;++i)                     // B: U cols = Wuv rows n0..n0+63
      GLDS16(Wuv + (size_t)(n0 + i*32 + sr)*512 + kc + scA, s + 9216 + i*2048 + tid*8);
    #pragma unroll
    for (int i=0;i<2;++i)                     // B: V cols = Wuv rows 512+n0..+63
      GLDS16(Wuv + (size_t)(512 + n0 + i*32 + sr)*512 + kc + scA, s + 13312 + i*2048 + tid*8);
  };

  stage(0, 0);
  stage(1, 1);
  for (int ks=0; ks<8; ++ks){
    const int cur = ks & 1;
    if (ks+1 < 8){
      if (wv < 2) asm volatile("s_waitcnt vmcnt(9)" ::: "memory");
      else        asm volatile("s_waitcnt vmcnt(8)" ::: "memory");
    } else        asm volatile("s_waitcnt vmcnt(0)" ::: "memory");
    __builtin_amdgcn_s_barrier();
    asm volatile("" ::: "memory");
    const unsigned short* s = smraw + cur*17408;
    #pragma unroll
    for (int kk=0;kk<2;++kk){
      const int ko = ((kk<<5) + (lg<<3)) ^ swzr;
      bf16x8 af[4], bU[2], bV[2];
      #pragma unroll
      for (int mi=0;mi<4;++mi)
        af[mi] = *(const bf16x8*)(s + ((wr<<6) + (mi<<4) + la)*64 + ko);
      #pragma unroll
      for (int ni=0;ni<2;++ni){
        bU[ni] = *(const bf16x8*)(s + 9216  + (((wc<<5) + (ni<<4) + la))*64 + ko);
        bV[ni] = *(const bf16x8*)(s + 13312 + (((wc<<5) + (ni<<4) + la))*64 + ko);
      }
      #pragma unroll
      for (int mi=0;mi<4;++mi)
        #pragma unroll
        for (int ni=0;ni<2;++ni){
          aU[mi][ni] = __builtin_amdgcn_mfma_f32_16x16x32_bf16(af[mi], bU[ni], aU[mi][ni], 0, 0, 0);
          aV[mi][ni] = __builtin_amdgcn_mfma_f32_16x16x32_bf16(af[mi], bV[ni], aV[mi][ni], 0, 0, 0);
        }
      if (wr == 0){
        bf16x8 afx = *(const bf16x8*)(s + 8192 + la*64 + ko);
        #pragma unroll
        for (int ni=0;ni<2;++ni)
          aX[ni] = __builtin_amdgcn_mfma_f32_16x16x32_bf16(afx, bV[ni], aX[ni], 0, 0, 0);
      }
    }
    asm volatile("" ::: "memory");
    __builtin_amdgcn_s_barrier();
    asm volatile("" ::: "memory");
    if (ks+2 < 8) stage(ks+2, cur);
  }

  // ---- epilogue: stage V (f32) into LDS [144][65], then windowed gelu-sum ----
  float* Vl = (float*)smraw;                  // 144*65*4 = 37440 B < 69632, staging dead
  const int colL = (wc<<5) + la;              // + ni*16
  #pragma unroll
  for (int mi=0;mi<4;++mi)
    #pragma unroll
    for (int ni=0;ni<2;++ni)
      #pragma unroll
      for (int q=0;q<4;++q)
        Vl[(16 + (wr<<6) + (mi<<4) + (lg<<2) + q)*65 + colL + (ni<<4)] = aV[mi][ni][q];
  if (wr == 0)
    #pragma unroll
    for (int ni=0;ni<2;++ni)
      #pragma unroll
      for (int q=0;q<4;++q)
        Vl[((lg<<2) + q)*65 + colL + (ni<<4)] = aX[ni][q];
  __syncthreads();

  const int ibase = m0 & (NSEQ-1);            // block never crosses a batch boundary
  #pragma unroll
  for (int mi=0;mi<4;++mi){
    #pragma unroll
    for (int ni=0;ni<2;++ni){
      const int cl = colL + (ni<<4);
      const float bs = biasU[n0 + cl];
      #pragma unroll
      for (int q=0;q<4;++q){
        const int rl = (wr<<6) + (mi<<4) + (lg<<2) + q;
        const int i  = ibase + rl;
        const int nd = (i<4) ? i : 4;
        const float u = aU[mi][ni][q] + bs;
        float g = 0.f;
        for (int d=0; d<=nd; ++d)
          g += geluf(u + Vl[(16 + rl - d)*65 + cl]);
        G[(size_t)(m0 + rl)*512 + n0 + cl] = f2bf(g/(float)(nd+1));
      }
    }
  }
}

// ================= fused: OUT accum (prev step) + LayerNorm(h+R) + halt-dot partial =================
__global__ __launch_bounds__(256) void k_ln(
    const float* __restrict__ Rr, float* __restrict__ H, unsigned short* __restrict__ Hb,
    const float* __restrict__ gamma, const float* __restrict__ beta,
    const float* __restrict__ hW, float* __restrict__ DOT, float* __restrict__ OUT,
    const float* __restrict__ scal, const int* __restrict__ flags,
    int accmode, int dodot)
{
  const int lane = threadIdx.x & 63;
  const int row = (blockIdx.x<<2) + (threadIdx.x>>6);
  const int bidx = row >> 11;
  const size_t base = (size_t)row*512 + lane*8;
  float4 x0 = *(const float4*)(H+base);
  float4 x1 = *(const float4*)(H+base+4);

  if (accmode){                      // H still holds h_prev; w=0 once inactive
    const float w = scal[4+bidx];
    float4 o0, o1;
    if (accmode==1){
      o0 = make_float4(w*x0.x, w*x0.y, w*x0.z, w*x0.w);
      o1 = make_float4(w*x1.x, w*x1.y, w*x1.z, w*x1.w);
    } else {
      o0 = *(const float4*)(OUT+base);
      o1 = *(const float4*)(OUT+base+4);
      o0.x += w*x0.x; o0.y += w*x0.y; o0.z += w*x0.z; o0.w += w*x0.w;
      o1.x += w*x1.x; o1.y += w*x1.y; o1.z += w*x1.z; o1.w += w*x1.w;
    }
    *(float4*)(OUT+base)   = o0;
    *(float4*)(OUT+base+4) = o1;
  }
  if (flags[0]==0) return;

  float4 r0 = *(const float4*)(Rr+base);
  float4 r1 = *(const float4*)(Rr+base+4);
  x0.x+=r0.x; x0.y+=r0.y; x0.z+=r0.z; x0.w+=r0.w;
  x1.x+=r1.x; x1.y+=r1.y; x1.z+=r1.z; x1.w+=r1.w;
  float s = x0.x+x0.y+x0.z+x0.w + x1.x+x1.y+x1.z+x1.w;
  float q = x0.x*x0.x+x0.y*x0.y+x0.z*x0.z+x0.w*x0.w
          + x1.x*x1.x+x1.y*x1.y+x1.z*x1.z+x1.w*x1.w;
  #pragma unroll
  for (int off=1; off<64; off<<=1){ s += __shfl_xor(s, off); q += __shfl_xor(q, off); }
  const float mean = s*(1.f/512.f);
  const float var  = q*(1.f/512.f) - mean*mean;
  const float rstd = rsqrtf(var + 1e-5f);
  float4 g0 = *(const float4*)(gamma + lane*8);
  float4 g1 = *(const float4*)(gamma + lane*8 + 4);
  float4 b0 = *(const float4*)(beta  + lane*8);
  float4 b1 = *(const float4*)(beta  + lane*8 + 4);
  float y[8];
  y[0]=(x0.x-mean)*rstd*g0.x+b0.x; y[1]=(x0.y-mean)*rstd*g0.y+b0.y;
  y[2]=(x0.z-mean)*rstd*g0.z+b0.z; y[3]=(x0.w-mean)*rstd*g0.w+b0.w;
  y[4]=(x1.x-mean)*rstd*g1.x+b1.x; y[5]=(x1.y-mean)*rstd*g1.y+b1.y;
  y[6]=(x1.z-mean)*rstd*g1.z+b1.z; y[7]=(x1.w-mean)*rstd*g1.w+b1.w;
  *(float4*)(H+base)   = make_float4(y[0],y[1],y[2],y[3]);
  *(float4*)(H+base+4) = make_float4(y[4],y[5],y[6],y[7]);
  u16x8 hb;
  #pragma unroll
  for (int j=0;j<8;++j) hb[j] = f2bf(y[j]);
  *(u16x8*)(Hb+base) = hb;

  if (dodot){
    float4 w0 = *(const float4*)(hW + lane*8);
    float4 w1 = *(const float4*)(hW + lane*8 + 4);
    float d = y[0]*w0.x + y[1]*w0.y + y[2]*w0.z + y[3]*w0.w
            + y[4]*w1.x + y[5]*w1.y + y[6]*w1.z + y[7]*w1.w;
    #pragma unroll
    for (int off=1; off<64; off<<=1) d += __shfl_xor(d, off);
    if (lane==0) DOT[row] = d;
  }
}

// ================= control: reduce DOT, halt / remaining / kl / done =================
__global__ void k_control(const float* __restrict__ DOT, const float* __restrict__ hb,
                          float* __restrict__ scal, int* __restrict__ flags,
                          int step, float p, float logp, float* __restrict__ klout)
{
  __shared__ float hp[4];
  const int t = threadIdx.x, lane = t&63, b = t>>6;
  if (step>=2 && step<5){
    float s = 0.f;
    for (int i=lane; i<NSEQ; i+=64) s += DOT[b*NSEQ + i];
    #pragma unroll
    for (int off=1; off<64; off<<=1) s += __shfl_xor(s, off);
    if (lane==0) hp[b] = s;
  } else if (lane==0) hp[b] = 0.f;
  __syncthreads();
  if (t==0){
    bool active = flags[0]!=0;
    float halt[NB];
    for (int i=0;i<NB;++i){
      if (step < 2) halt[i]=0.f;
      else if (step == 5) halt[i]=1.f;
      else { float z = hp[i]*(1.f/2048.f) + hb[0]; halt[i] = 1.f/(1.f+expf(-z)); }
    }
    float hm = 0.25f*(halt[0]+halt[1]+halt[2]+halt[3]);
    if (active) scal[8] += p*(logp - logf(hm + 1e-8f));
    float mx = 0.f;
    for (int i=0;i<NB;++i){
      float rb = scal[i];
      float w  = active ? rb*halt[i] : 0.f;
      scal[4+i] = w;
      if (active) rb *= (1.f - halt[i]);
      scal[i] = rb;
      mx = fmaxf(mx, rb);
    }
    if (mx < 0.01f) flags[1] = 1;
    flags[0] = flags[1] ? 0 : 1;
    if (step==5) *klout = scal[8]*(1.0f/6.0f);
  }
}

// ================= OUT += w_b * H (final step only) =================
__global__ __launch_bounds__(256) void k_accum(
    const float* __restrict__ H, const float* __restrict__ scal, float* __restrict__ OUT)
{
  size_t idx = (size_t)blockIdx.x*256 + threadIdx.x;   // float4 units, < 1048576
  int b = (int)(idx >> 18);                            // 262144 float4 per batch
  float w = scal[4+b];
  float4 h = ((const float4*)H)[idx];
  float4 o = ((float4*)OUT)[idx];
  ((float4*)OUT)[idx] = make_float4(o.x+w*h.x, o.y+w*h.y, o.z+w*h.z, o.w+w*h.w);
}

extern "C" void kernel_launch(void* const* d_in, const int* in_sizes, int n_in,
                              void* d_out, int out_size, void* d_ws, size_t ws_size,
                              hipStream_t stream)
{
  const float* S   = (const float*)d_in[0];
  const float* mW1 = (const float*)d_in[1];
  const float* mb1 = (const float*)d_in[2];
  const float* mW2 = (const float*)d_in[3];
  const float* mb2 = (const float*)d_in[4];
  const float* uW1 = (const float*)d_in[5];
  const float* ub1 = (const float*)d_in[6];
  const float* uW2 = (const float*)d_in[7];
  const float* ub2 = (const float*)d_in[8];
  const float* hW  = (const float*)d_in[9];
  const float* hb  = (const float*)d_in[10];
  const float* lng = (const float*)d_in[11];
  const float* lnb = (const float*)d_in[12];

  char* ws = (char*)d_ws;
  float*          H     = (float*)(ws + OFF_H);
  unsigned short* Hb    = (unsigned short*)(ws + OFF_HB);
  unsigned short* GP    = (unsigned short*)(ws + OFF_GP);
  unsigned short* GSC   = (unsigned short*)(ws + OFF_GSC);
  float*          Rb    = (float*)(ws + OFF_R);
  unsigned short* Wuv   = (unsigned short*)(ws + OFF_WUV);
  unsigned short* Wp    = (unsigned short*)(ws + OFF_WP);
  unsigned short* Wr    = (unsigned short*)(ws + OFF_WR);
  unsigned short* A2    = (unsigned short*)(ws + OFF_A2);
  unsigned short* B2    = (unsigned short*)(ws + OFF_B2);
  float*          biasUV= (float*)(ws + OFF_BUV);
  float*          biasP = (float*)(ws + OFF_BP);
  float*          biasR = (float*)(ws + OFF_BR);
  float*          DOT   = (float*)(ws + OFF_DOT);
  float*          scal  = (float*)(ws + OFF_SCAL);
  int*            flags = (int*)(ws + OFF_FLAGS);
  float*          OUT   = (float*)d_out;
  float*          klout = OUT + (size_t)NB*NSEQ*DDIM;

  // ---- state + weight prep (deterministic, inside the graph) ----
  k_init_state<<<1, 256, 0, stream>>>(scal, flags);
  k_prep_tr   <<<dim3(64,5), 256, 0, stream>>>(mW1, uW2, uW1, Wuv, Wr, Wp, A2);
  k_prep_small<<<1032, 256, 0, stream>>>(mW2, mb1, ub2, B2, biasUV, biasR);
  k_prep_biasP<<<2,    256, 0, stream>>>(ub1, mb2, uW1, biasP);
  // Wp upper K-half: (msgW2 @ updW1_bot)^T via MFMA; C[n][a] -> Wp[n*1024+512+a]
  k_gemm<0><<<32, 256, 0, stream>>>(A2, A2, B2, biasUV+512, Wp+512, 1024, 512, 8, 8, 8, flags);
  k_init_h    <<<4096, 256, 0, stream>>>(S, H, (u16x4*)Hb);

  for (int s = 0; s < 6; ++s){
    // GSC = windowed gelu-mean of message MLP hidden (fused gemm0+geluacc)
    k_gmsg<<<512, 256, 0, stream>>>(Hb, Wuv, biasUV, GSC, flags);
    // GP = gelu( Hb@updW1_top + GSC@(msgW2@updW1_bot) + biasP )
    k_gemm<1><<<512, 256, 0, stream>>>(Hb, GSC, Wp, biasP, GP, 512, 1024, 16, 8, 8, flags);
    // R = GP @ updW2 + upd_b2  (f32)
    k_gemm<2><<<512, 256, 0, stream>>>(GP, GP, Wr, biasR, Rb, 512, 512, 8, 8, 8, flags);
    // OUT accum of h_{s-1}, then h = LN(h + R), then halt dot
    const int accmode = (s==3) ? 1 : (s>=4 ? 2 : 0);
    const int dodot   = (s>=2 && s<=4) ? 1 : 0;
    k_ln<<<2048, 256, 0, stream>>>(Rb, H, Hb, lng, lnb, hW, DOT, OUT, scal, flags, accmode, dodot);
    float p = 0.2f * (float)pow(0.8, (double)s);
    float lp = (float)log((double)p);
    k_control<<<1, 256, 0, stream>>>(DOT, hb, scal, flags, s, p, lp, klout);
  }
  // final step's weighted h (w_5)
  k_accum<<<4096, 256, 0, stream>>>(H, scal, OUT);
}

// Round 8
// 553.939 us; speedup vs baseline: 1.5531x; 1.5531x over previous
//
#include <hip/hip_runtime.h>
#include <cmath>

#define DEV __device__ __forceinline__

typedef __bf16 bf16x8 __attribute__((ext_vector_type(8)));
typedef float f32x4v __attribute__((ext_vector_type(4)));
typedef unsigned short u16x8 __attribute__((ext_vector_type(8)));
typedef unsigned short u16x4 __attribute__((ext_vector_type(4)));

DEV float bf2f(unsigned short u){ return __uint_as_float(((unsigned)u)<<16); }
DEV unsigned short f2bf(float f){
  unsigned u = __float_as_uint(f);
  u = (u + 0x7fffu + ((u>>16)&1u)) >> 16;
  return (unsigned short)u;
}
// exact-GELU via branchless A&S 7.1.26 erf (|eps| <= 1.5e-7): ~15 straight-line VALU ops
// vs ROCm erff's ~60 divergent. Error invisible under bf16 rounding (absmax margin 3x).
DEV float geluf(float x){
  const float z = fabsf(x) * 0.70710678118654752f;
  const float t = __builtin_amdgcn_rcpf(1.0f + 0.3275911f*z);
  const float p = t*(0.254829592f + t*(-0.284496736f + t*(1.421413741f
                + t*(-1.453152027f + t*1.061405429f))));
  float er = 1.0f - p*__expf(-z*z);      // erf(|x|/sqrt2)
  er = (x < 0.0f) ? -er : er;
  return 0.5f*x*(1.0f + er);
}

#define GLDS16(g,l) __builtin_amdgcn_global_load_lds(\
    (const __attribute__((address_space(1))) void*)(g), \
    (__attribute__((address_space(3))) void*)(l), 16, 0, 0)

// ---- problem constants ----
#define NB    4
#define NSEQ  2048
#define DDIM  512
#define MROWS 8192   // NB*NSEQ

// ---- workspace layout (bytes) ----
#define OFF_H     0u           // f32  8192x512   (16M)
#define OFF_HB    16777216u    // bf16 8192x512   (8M)
#define OFF_UV    25165824u    // bf16 8192x1024  (16M)  (prep: A2/B2 live here first)
#define OFF_GP    25165824u    // bf16 8192x512   (8M)   aliases UV (UV dead after geluacc)
#define OFF_R     33554432u    // f32  8192x512   (16M)  aliases UV hi
#define OFF_GSC   41943040u    // bf16 8192x512   (8M)
#define OFF_WUV   50331648u    // bf16 1024x512 (Wuv^T)
#define OFF_WP    51380224u    // bf16 512x1024 (Wp^T: [updW1_top^T | (msgW2@updW1_bot)^T])
#define OFF_WR    52428800u    // bf16 512x512  (updW2^T)
#define OFF_BUV   52953088u    // f32[1024]  (mb1 | zeros)
#define OFF_BP    52957184u    // f32[512]
#define OFF_BR    52959232u    // f32[512]
#define OFF_DOT   52961280u    // f32[8192] per-row halt-dot partials (32K)
#define OFF_SCAL  52994048u    // f32: [0..3] remaining, [4..7] w_step, [8] kl
#define OFF_FLAGS 52994112u    // int: [0] active, [1] done
// prep-only (aliases UV; dead before first gemm0 writes UV):
#define OFF_A2    25165824u    // bf16 512x512: (uW1_bot)^T
#define OFF_B2    25690112u    // bf16 512x512: mW2

// ================= prep: LDS-tiled 512x512 f32->bf16 transposes =================
__global__ __launch_bounds__(256) void k_prep_tr(
    const float* __restrict__ mW1, const float* __restrict__ uW2,
    const float* __restrict__ uW1,
    unsigned short* __restrict__ Wuv, unsigned short* __restrict__ Wr,
    unsigned short* __restrict__ Wp,  unsigned short* __restrict__ A2)
{
  __shared__ float t[64][65];
  const int tid = threadIdx.x, c = tid&63, r4 = tid>>6;
  const float* src; unsigned short* dst; int dld;
  switch (blockIdx.y){
    case 0: src = mW1;          dst = Wuv;          dld = 512;  break;
    case 1: src = mW1 + 262144; dst = Wuv + 262144; dld = 512;  break;
    case 2: src = uW2;          dst = Wr;           dld = 512;  break;
    case 3: src = uW1;          dst = Wp;           dld = 1024; break;
    default:src = uW1 + 262144; dst = A2;           dld = 512;  break;
  }
  const int k0 = (blockIdx.x>>3)<<6, n0 = (blockIdx.x&7)<<6;
  #pragma unroll
  for (int i=0;i<16;++i){ int r = i*4 + r4; t[r][c] = src[(size_t)(k0+r)*512 + n0 + c]; }
  __syncthreads();
  #pragma unroll
  for (int i=0;i<16;++i){ int r = i*4 + r4; dst[(size_t)(n0+r)*dld + k0 + c] = f2bf(t[c][r]); }
}

// B2 copy + biasUV + biasR
__global__ __launch_bounds__(256) void k_prep_small(
    const float* __restrict__ mW2, const float* __restrict__ mb1,
    const float* __restrict__ ub2,
    unsigned short* __restrict__ B2, float* __restrict__ biasUV,
    float* __restrict__ biasR)
{
  int idx = blockIdx.x*256 + threadIdx.x;
  if (idx < 262144)      B2[idx] = f2bf(mW2[idx]);
  else if (idx < 263168){ int j = idx-262144; biasUV[j] = (j<512)? mb1[j] : 0.f; }
  else if (idx < 263680){ int j = idx-263168; biasR[j] = ub2[j]; }
}

// biasP[n] = upd_b1[n] + msg_b2 @ updW1_bot[:,n]
__global__ __launch_bounds__(256) void k_prep_biasP(
    const float* __restrict__ ub1, const float* __restrict__ mb2,
    const float* __restrict__ uW1, float* __restrict__ biasP)
{
  int n = blockIdx.x*256 + threadIdx.x;
  float s = ub1[n];
  for (int j=0;j<512;++j) s += mb2[j]*uW1[(512+j)*512+n];
  biasP[n] = s;
}

__global__ void k_init_state(float* scal, int* flags){
  int t = threadIdx.x;
  if (t<4) scal[t]=1.f;
  else if (t<9) scal[t]=0.f;
  if (t==9){ flags[0]=1; flags[1]=0; }
}

__global__ __launch_bounds__(256) void k_init_h(
    const float* __restrict__ S, float* __restrict__ H, u16x4* __restrict__ Hb)
{
  size_t idx = (size_t)blockIdx.x*256 + threadIdx.x;   // float4 units, < 1048576
  float4 v = ((const float4*)S)[idx];
  ((float4*)H)[idx] = v;
  u16x4 o; o[0]=f2bf(v.x); o[1]=f2bf(v.y); o[2]=f2bf(v.z); o[3]=f2bf(v.w);
  Hb[idx] = o;
}

// ================= MFMA GEMM: C = A(Mx512 bf16 [A1 for k>=ksplit*64]) @ Bt^T =================
// 128x64 tile, BK=64, 4 waves 2x2, double-buffered LDS, counted-vmcnt pipeline (R6 proven):
// 2 tiles in flight, s_waitcnt vmcnt(6) + raw s_barrier — prefetched loads stay in flight
// across the barrier. T2 XOR-swizzle; XCD-chunked block map.
template<int EPI>  // 0: bias+bf16 out, 1: bias+gelu+bf16 out, 2: bias+f32 out
__global__ __launch_bounds__(256) void k_gemm(
    const unsigned short* __restrict__ A0, const unsigned short* __restrict__ A1,
    const unsigned short* __restrict__ Bt, const float* __restrict__ bias,
    void* __restrict__ Cout, int ldc, int ldb, int nK, int ksplit, int gridN,
    const int* __restrict__ flags)
{
  if (flags[0]==0) return;
  __shared__ unsigned short sm[2][12288];
  const int tid = threadIdx.x;
  const int bid = blockIdx.x;
  const int nb  = (int)gridDim.x;
  const int ppx = (nb>>3)/gridN;
  int mp, np;
  if (ppx*gridN*8 == nb){ const int xcd = bid&7, ib = bid>>3; mp = xcd*ppx + ib/gridN; np = ib%gridN; }
  else                  { mp = bid/gridN; np = bid%gridN; }
  const int m0 = mp<<7, n0 = np<<6;
  const int sr = tid>>3;
  const int scA = (((tid&7) ^ (sr&7)) << 3);
  const int lane = tid&63, wv = tid>>6, wr = wv>>1, wc = wv&1;
  const int la = lane&15, lg = lane>>4;
  const int swzr = (la&7)<<3;
  f32x4v acc[4][2] = {};

  auto stage = [&](int ks, int bufi){                  // 6 GLDS16 per thread
    const unsigned short* As = (ks<ksplit)? A0 : A1;
    const int kc = ((ks<ksplit)? ks : (ks-ksplit))<<6;
    unsigned short* s = sm[bufi];
    #pragma unroll
    for (int i=0;i<4;++i)
      GLDS16(As + (size_t)(m0 + i*32 + sr)*512 + kc + scA, s + i*2048 + tid*8);
    #pragma unroll
    for (int i=0;i<2;++i)
      GLDS16(Bt + (size_t)(n0 + i*32 + sr)*ldb + (ks<<6) + scA, s + 8192 + i*2048 + tid*8);
  };

  stage(0, 0);
  if (nK > 1) stage(1, 1);
  for (int ks=0; ks<nK; ++ks){
    const int cur = ks & 1;
    if (ks+1 < nK) asm volatile("s_waitcnt vmcnt(6)" ::: "memory");
    else           asm volatile("s_waitcnt vmcnt(0)" ::: "memory");
    __builtin_amdgcn_s_barrier();
    asm volatile("" ::: "memory");
    const unsigned short* s = sm[cur];
    #pragma unroll
    for (int kk=0;kk<2;++kk){
      bf16x8 af[4], bfr[2];
      #pragma unroll
      for (int mi=0;mi<4;++mi)
        af[mi] = *(const bf16x8*)(s + ((wr<<6) + (mi<<4) + la)*64 + (((kk<<5) + (lg<<3)) ^ swzr));
      #pragma unroll
      for (int ni=0;ni<2;++ni)
        bfr[ni] = *(const bf16x8*)(s + 8192 + ((wc<<5) + (ni<<4) + la)*64 + (((kk<<5) + (lg<<3)) ^ swzr));
      #pragma unroll
      for (int mi=0;mi<4;++mi)
        #pragma unroll
        for (int ni=0;ni<2;++ni)
          acc[mi][ni] = __builtin_amdgcn_mfma_f32_16x16x32_bf16(af[mi], bfr[ni], acc[mi][ni], 0, 0, 0);
    }
    asm volatile("" ::: "memory");
    __builtin_amdgcn_s_barrier();
    asm volatile("" ::: "memory");
    if (ks+2 < nK) stage(ks+2, cur);
  }

  const int r0 = m0 + (wr<<6) + (lg<<2);
  const int c0 = n0 + (wc<<5) + la;
  #pragma unroll
  for (int mi=0;mi<4;++mi){
    #pragma unroll
    for (int ni=0;ni<2;++ni){
      const int col = c0 + (ni<<4);
      const float bs = bias[col];
      #pragma unroll
      for (int r=0;r<4;++r){
        const int row = r0 + (mi<<4) + r;
        float v = acc[mi][ni][r] + bs;
        if constexpr (EPI==1) v = geluf(v);
        if constexpr (EPI==2) ((float*)Cout)[(size_t)row*ldc + col] = v;
        else ((unsigned short*)Cout)[(size_t)row*ldc + col] = f2bf(v);
      }
    }
  }
}

// ================= G[i] = (sum_{d<=min(i,4)} gelu(U[i]+V[i-d])) / count =================
__global__ __launch_bounds__(256) void k_geluacc(
    const unsigned short* __restrict__ UV, unsigned short* __restrict__ G,
    const int* __restrict__ flags)
{
  if (flags[0]==0) return;
  int r = blockIdx.x*4 + (threadIdx.x>>6);
  int lane = threadIdx.x & 63;
  int c8 = lane*8;
  int i = r & (NSEQ-1);
  int nd = (i<4) ? i : 4;
  const u16x8 u = *(const u16x8*)(UV + (size_t)r*1024 + c8);
  float acc[8] = {0,0,0,0,0,0,0,0};
  for (int d=0; d<=nd; ++d){
    const u16x8 v = *(const u16x8*)(UV + (size_t)(r-d)*1024 + 512 + c8);
    #pragma unroll
    for (int j=0;j<8;++j) acc[j] += geluf(bf2f(u[j]) + bf2f(v[j]));
  }
  float inv = 1.0f/(float)(nd+1);
  u16x8 o;
  #pragma unroll
  for (int j=0;j<8;++j) o[j] = f2bf(acc[j]*inv);
  *(u16x8*)(G + (size_t)r*512 + c8) = o;
}

// ================= fused: OUT accum (prev step) + LayerNorm(h+R) + halt-dot partial =================
__global__ __launch_bounds__(256) void k_ln(
    const float* __restrict__ Rr, float* __restrict__ H, unsigned short* __restrict__ Hb,
    const float* __restrict__ gamma, const float* __restrict__ beta,
    const float* __restrict__ hW, float* __restrict__ DOT, float* __restrict__ OUT,
    const float* __restrict__ scal, const int* __restrict__ flags,
    int accmode, int dodot)
{
  const int lane = threadIdx.x & 63;
  const int row = (blockIdx.x<<2) + (threadIdx.x>>6);
  const int bidx = row >> 11;
  const size_t base = (size_t)row*512 + lane*8;
  float4 x0 = *(const float4*)(H+base);
  float4 x1 = *(const float4*)(H+base+4);

  if (accmode){                      // H still holds h_prev; w=0 once inactive
    const float w = scal[4+bidx];
    float4 o0, o1;
    if (accmode==1){
      o0 = make_float4(w*x0.x, w*x0.y, w*x0.z, w*x0.w);
      o1 = make_float4(w*x1.x, w*x1.y, w*x1.z, w*x1.w);
    } else {
      o0 = *(const float4*)(OUT+base);
      o1 = *(const float4*)(OUT+base+4);
      o0.x += w*x0.x; o0.y += w*x0.y; o0.z += w*x0.z; o0.w += w*x0.w;
      o1.x += w*x1.x; o1.y += w*x1.y; o1.z += w*x1.z; o1.w += w*x1.w;
    }
    *(float4*)(OUT+base)   = o0;
    *(float4*)(OUT+base+4) = o1;
  }
  if (flags[0]==0) return;

  float4 r0 = *(const float4*)(Rr+base);
  float4 r1 = *(const float4*)(Rr+base+4);
  x0.x+=r0.x; x0.y+=r0.y; x0.z+=r0.z; x0.w+=r0.w;
  x1.x+=r1.x; x1.y+=r1.y; x1.z+=r1.z; x1.w+=r1.w;
  float s = x0.x+x0.y+x0.z+x0.w + x1.x+x1.y+x1.z+x1.w;
  float q = x0.x*x0.x+x0.y*x0.y+x0.z*x0.z+x0.w*x0.w
          + x1.x*x1.x+x1.y*x1.y+x1.z*x1.z+x1.w*x1.w;
  #pragma unroll
  for (int off=1; off<64; off<<=1){ s += __shfl_xor(s, off); q += __shfl_xor(q, off); }
  const float mean = s*(1.f/512.f);
  const float var  = q*(1.f/512.f) - mean*mean;
  const float rstd = rsqrtf(var + 1e-5f);
  float4 g0 = *(const float4*)(gamma + lane*8);
  float4 g1 = *(const float4*)(gamma + lane*8 + 4);
  float4 b0 = *(const float4*)(beta  + lane*8);
  float4 b1 = *(const float4*)(beta  + lane*8 + 4);
  float y[8];
  y[0]=(x0.x-mean)*rstd*g0.x+b0.x; y[1]=(x0.y-mean)*rstd*g0.y+b0.y;
  y[2]=(x0.z-mean)*rstd*g0.z+b0.z; y[3]=(x0.w-mean)*rstd*g0.w+b0.w;
  y[4]=(x1.x-mean)*rstd*g1.x+b1.x; y[5]=(x1.y-mean)*rstd*g1.y+b1.y;
  y[6]=(x1.z-mean)*rstd*g1.z+b1.z; y[7]=(x1.w-mean)*rstd*g1.w+b1.w;
  *(float4*)(H+base)   = make_float4(y[0],y[1],y[2],y[3]);
  *(float4*)(H+base+4) = make_float4(y[4],y[5],y[6],y[7]);
  u16x8 hb;
  #pragma unroll
  for (int j=0;j<8;++j) hb[j] = f2bf(y[j]);
  *(u16x8*)(Hb+base) = hb;

  if (dodot){
    float4 w0 = *(const float4*)(hW + lane*8);
    float4 w1 = *(const float4*)(hW + lane*8 + 4);
    float d = y[0]*w0.x + y[1]*w0.y + y[2]*w0.z + y[3]*w0.w
            + y[4]*w1.x + y[5]*w1.y + y[6]*w1.z + y[7]*w1.w;
    #pragma unroll
    for (int off=1; off<64; off<<=1) d += __shfl_xor(d, off);
    if (lane==0) DOT[row] = d;
  }
}

// ================= control: reduce DOT, halt / remaining / kl / done =================
__global__ void k_control(const float* __restrict__ DOT, const float* __restrict__ hb,
                          float* __restrict__ scal, int* __restrict__ flags,
                          int step, float p, float logp, float* __restrict__ klout)
{
  __shared__ float hp[4];
  const int t = threadIdx.x, lane = t&63, b = t>>6;
  if (step>=2 && step<5){
    float s = 0.f;
    for (int i=lane; i<NSEQ; i+=64) s += DOT[b*NSEQ + i];
    #pragma unroll
    for (int off=1; off<64; off<<=1) s += __shfl_xor(s, off);
    if (lane==0) hp[b] = s;
  } else if (lane==0) hp[b] = 0.f;
  __syncthreads();
  if (t==0){
    bool active = flags[0]!=0;
    float halt[NB];
    for (int i=0;i<NB;++i){
      if (step < 2) halt[i]=0.f;
      else if (step == 5) halt[i]=1.f;
      else { float z = hp[i]*(1.f/2048.f) + hb[0]; halt[i] = 1.f/(1.f+expf(-z)); }
    }
    float hm = 0.25f*(halt[0]+halt[1]+halt[2]+halt[3]);
    if (active) scal[8] += p*(logp - logf(hm + 1e-8f));
    float mx = 0.f;
    for (int i=0;i<NB;++i){
      float rb = scal[i];
      float w  = active ? rb*halt[i] : 0.f;
      scal[4+i] = w;
      if (active) rb *= (1.f - halt[i]);
      scal[i] = rb;
      mx = fmaxf(mx, rb);
    }
    if (mx < 0.01f) flags[1] = 1;
    flags[0] = flags[1] ? 0 : 1;
    if (step==5) *klout = scal[8]*(1.0f/6.0f);
  }
}

// ================= OUT += w_b * H (final step only) =================
__global__ __launch_bounds__(256) void k_accum(
    const float* __restrict__ H, const float* __restrict__ scal, float* __restrict__ OUT)
{
  size_t idx = (size_t)blockIdx.x*256 + threadIdx.x;   // float4 units, < 1048576
  int b = (int)(idx >> 18);                            // 262144 float4 per batch
  float w = scal[4+b];
  float4 h = ((const float4*)H)[idx];
  float4 o = ((float4*)OUT)[idx];
  ((float4*)OUT)[idx] = make_float4(o.x+w*h.x, o.y+w*h.y, o.z+w*h.z, o.w+w*h.w);
}

extern "C" void kernel_launch(void* const* d_in, const int* in_sizes, int n_in,
                              void* d_out, int out_size, void* d_ws, size_t ws_size,
                              hipStream_t stream)
{
  const float* S   = (const float*)d_in[0];
  const float* mW1 = (const float*)d_in[1];
  const float* mb1 = (const float*)d_in[2];
  const float* mW2 = (const float*)d_in[3];
  const float* mb2 = (const float*)d_in[4];
  const float* uW1 = (const float*)d_in[5];
  const float* ub1 = (const float*)d_in[6];
  const float* uW2 = (const float*)d_in[7];
  const float* ub2 = (const float*)d_in[8];
  const float* hW  = (const float*)d_in[9];
  const float* hb  = (const float*)d_in[10];
  const float* lng = (const float*)d_in[11];
  const float* lnb = (const float*)d_in[12];

  char* ws = (char*)d_ws;
  float*          H     = (float*)(ws + OFF_H);
  unsigned short* Hb    = (unsigned short*)(ws + OFF_HB);
  unsigned short* UV    = (unsigned short*)(ws + OFF_UV);
  unsigned short* GP    = (unsigned short*)(ws + OFF_GP);
  unsigned short* GSC   = (unsigned short*)(ws + OFF_GSC);
  float*          Rb    = (float*)(ws + OFF_R);
  unsigned short* Wuv   = (unsigned short*)(ws + OFF_WUV);
  unsigned short* Wp    = (unsigned short*)(ws + OFF_WP);
  unsigned short* Wr    = (unsigned short*)(ws + OFF_WR);
  unsigned short* A2    = (unsigned short*)(ws + OFF_A2);
  unsigned short* B2    = (unsigned short*)(ws + OFF_B2);
  float*          biasUV= (float*)(ws + OFF_BUV);
  float*          biasP = (float*)(ws + OFF_BP);
  float*          biasR = (float*)(ws + OFF_BR);
  float*          DOT   = (float*)(ws + OFF_DOT);
  float*          scal  = (float*)(ws + OFF_SCAL);
  int*            flags = (int*)(ws + OFF_FLAGS);
  float*          OUT   = (float*)d_out;
  float*          klout = OUT + (size_t)NB*NSEQ*DDIM;

  // ---- state + weight prep (deterministic, inside the graph) ----
  k_init_state<<<1, 256, 0, stream>>>(scal, flags);
  k_prep_tr   <<<dim3(64,5), 256, 0, stream>>>(mW1, uW2, uW1, Wuv, Wr, Wp, A2);
  k_prep_small<<<1032, 256, 0, stream>>>(mW2, mb1, ub2, B2, biasUV, biasR);
  k_prep_biasP<<<2,    256, 0, stream>>>(ub1, mb2, uW1, biasP);
  // Wp upper K-half: (msgW2 @ updW1_bot)^T via MFMA; C[n][a] -> Wp[n*1024+512+a]
  k_gemm<0><<<32, 256, 0, stream>>>(A2, A2, B2, biasUV+512, Wp+512, 1024, 512, 8, 8, 8, flags);
  k_init_h    <<<4096, 256, 0, stream>>>(S, H, (u16x4*)Hb);

  for (int s = 0; s < 6; ++s){
    // UV = Hb @ [msgW1_top | msgW1_bot] (+b1 on U half)
    k_gemm<0><<<1024, 256, 0, stream>>>(Hb, Hb, Wuv, biasUV, UV, 1024, 512, 8, 8, 16, flags);
    // G = windowed gelu-accumulate / counts
    k_geluacc<<<2048, 256, 0, stream>>>(UV, GSC, flags);
    // GP = gelu( Hb@updW1_top + GSC@(msgW2@updW1_bot) + biasP )
    k_gemm<1><<<512, 256, 0, stream>>>(Hb, GSC, Wp, biasP, GP, 512, 1024, 16, 8, 8, flags);
    // R = GP @ updW2 + upd_b2  (f32)
    k_gemm<2><<<512, 256, 0, stream>>>(GP, GP, Wr, biasR, Rb, 512, 512, 8, 8, 8, flags);
    // OUT accum of h_{s-1}, then h = LN(h + R), then halt dot
    const int accmode = (s==3) ? 1 : (s>=4 ? 2 : 0);
    const int dodot   = (s>=2 && s<=4) ? 1 : 0;
    k_ln<<<2048, 256, 0, stream>>>(Rb, H, Hb, lng, lnb, hW, DOT, OUT, scal, flags, accmode, dodot);
    float p = 0.2f * (float)pow(0.8, (double)s);
    float lp = (float)log((double)p);
    k_control<<<1, 256, 0, stream>>>(DOT, hb, scal, flags, s, p, lp, klout);
  }
  // final step's weighted h (w_5)
  k_accum<<<4096, 256, 0, stream>>>(H, scal, OUT);
}